// Round 1
// baseline (299.949 us; speedup 1.0000x reference)
//
#include <hip/hip_runtime.h>
#include <hip/hip_bf16.h>

#define N_ATOMS 20000
#define N_BONDS 200000
#define MAX_DEG 12
#define IN_DIM 256
#define BOND_DIM 128
#define OUT_DIM 512
#define N_HEADS 8
#define HEAD_DIM 64

typedef __attribute__((ext_vector_type(8))) short short8v;
typedef __attribute__((ext_vector_type(4))) float f32x4;

static __device__ __forceinline__ float bf2f(unsigned int u) {
    union { unsigned int i; float f; } c;
    c.i = (u & 0xffffu) << 16;
    return c.f;
}
static __device__ __forceinline__ unsigned short f2bf(float f) {
    union { float f; unsigned int i; } c;
    c.f = f;
    unsigned int x = c.i;
    x += 0x7fffu + ((x >> 16) & 1u);   // round-to-nearest-even
    return (unsigned short)(x >> 16);
}

// ---------------------------------------------------------------------------
// Wt[n][k] = bf16(W[k][n])  (N fixed 512)
// ---------------------------------------------------------------------------
__global__ void wt_kernel(const float* __restrict__ W, unsigned short* __restrict__ Wt,
                          int K) {
    int id = blockIdx.x * 256 + threadIdx.x;
    if (id >= K * 512) return;
    int n = id / K, k = id % K;
    Wt[id] = f2bf(W[(size_t)k * 512 + n]);
}

// ---------------------------------------------------------------------------
// H[m][512] (bf16) = A[m][K] (f32) @ Wt^T + bias.  Tiles 64x64x64, 4 waves.
// ---------------------------------------------------------------------------
__global__ __launch_bounds__(256) void gemm_kernel(
    const float* __restrict__ A, const unsigned short* __restrict__ Wt,
    const float* __restrict__ bias, unsigned short* __restrict__ H,
    int M, int K) {
    __shared__ unsigned short Als[64 * 64];
    __shared__ unsigned short Bls[64 * 64];
    const int t = threadIdx.x;
    const int bid = blockIdx.x;
    const int bn = bid & 7;        // 8 col tiles (N=512)
    const int bm = bid >> 3;
    const int w = t >> 6;          // wave 0..3
    const int l = t & 63;

    f32x4 acc[4] = {};

    const int nk = K >> 6;
    for (int kk = 0; kk < nk; ++kk) {
        // ---- stage A tile [64 m][64 k] f32 -> bf16, XOR-swizzled ----
        #pragma unroll
        for (int i = 0; i < 2; ++i) {
            int c = t + i * 256;           // 0..511
            int row = c >> 3;              // 0..63
            int k8 = (c & 7) << 3;         // 0,8,..,56
            int grow = (bm << 6) + row;
            float f[8];
            if (grow < M) {
                const float* src = A + (size_t)grow * K + (kk << 6) + k8;
                float4 v0 = *(const float4*)src;
                float4 v1 = *(const float4*)(src + 4);
                f[0] = v0.x; f[1] = v0.y; f[2] = v0.z; f[3] = v0.w;
                f[4] = v1.x; f[5] = v1.y; f[6] = v1.z; f[7] = v1.w;
            } else {
                #pragma unroll
                for (int j = 0; j < 8; ++j) f[j] = 0.f;
            }
            union { unsigned short us[8]; uint4 v; } pk;
            #pragma unroll
            for (int j = 0; j < 8; ++j) pk.us[j] = f2bf(f[j]);
            int byte = ((row << 7) + (k8 << 1)) ^ ((row & 7) << 4);
            *(uint4*)((char*)Als + byte) = pk.v;
        }
        // ---- stage B tile [64 n][64 k] bf16 (from Wt), XOR-swizzled ----
        #pragma unroll
        for (int i = 0; i < 2; ++i) {
            int c = t + i * 256;
            int row = c >> 3;              // n within tile
            int k8 = (c & 7) << 3;
            int gn = (bn << 6) + row;      // < 512 always
            uint4 v = *(const uint4*)(Wt + (size_t)gn * K + (kk << 6) + k8);
            int byte = ((row << 7) + (k8 << 1)) ^ ((row & 7) << 4);
            *(uint4*)((char*)Bls + byte) = v;
        }
        __syncthreads();

        const int m = l & 15;
        const int kg = (l >> 4) << 3;
        #pragma unroll
        for (int ks = 0; ks < 2; ++ks) {
            int kcol = (ks << 5) + kg;
            int arow = (w << 4) + m;
            short8v a = *(short8v*)((char*)Als +
                (((arow << 7) + (kcol << 1)) ^ ((arow & 7) << 4)));
            #pragma unroll
            for (int nt = 0; nt < 4; ++nt) {
                int nrow = (nt << 4) + m;
                short8v b = *(short8v*)((char*)Bls +
                    (((nrow << 7) + (kcol << 1)) ^ ((nrow & 7) << 4)));
                acc[nt] = __builtin_amdgcn_mfma_f32_16x16x32_bf16(a, b, acc[nt], 0, 0, 0);
            }
        }
        __syncthreads();
    }

    // ---- epilogue: C row = (l>>4)*4 + r, col = l&15 (verified layout) ----
    const int m = l & 15;
    const int rbase = (bm << 6) + (w << 4) + ((l >> 4) << 2);
    #pragma unroll
    for (int nt = 0; nt < 4; ++nt) {
        int col = (bn << 6) + (nt << 4) + m;
        float bv = bias[col];
        #pragma unroll
        for (int r = 0; r < 4; ++r) {
            int grow = rbase + r;
            if (grow < M) H[(size_t)grow * 512 + col] = f2bf(acc[nt][r] + bv);
        }
    }
}

// ---------------------------------------------------------------------------
// Fused gather + attention + softmax(deg) + weighted sum.
// One wave per atom; lane l owns channels [l*8, l*8+8) = head l>>3.
// ---------------------------------------------------------------------------
__global__ __launch_bounds__(256) void attn_kernel(
    const unsigned short* __restrict__ hA,
    const unsigned short* __restrict__ hB,
    const float* __restrict__ att_src,
    const float* __restrict__ att_dst,
    const float* __restrict__ att_edge,
    const int* __restrict__ a2a,
    const int* __restrict__ a2b,
    float* __restrict__ out) {
    const int w = threadIdx.x >> 6;
    const int l = threadIdx.x & 63;
    const int n = blockIdx.x * 4 + w;
    if (n >= N_ATOMS) return;

    float as[8], ad[8], ae[8];
    {
        float4 v0 = *(const float4*)(att_src + l * 8);
        float4 v1 = *(const float4*)(att_src + l * 8 + 4);
        as[0]=v0.x; as[1]=v0.y; as[2]=v0.z; as[3]=v0.w;
        as[4]=v1.x; as[5]=v1.y; as[6]=v1.z; as[7]=v1.w;
        v0 = *(const float4*)(att_dst + l * 8);
        v1 = *(const float4*)(att_dst + l * 8 + 4);
        ad[0]=v0.x; ad[1]=v0.y; ad[2]=v0.z; ad[3]=v0.w;
        ad[4]=v1.x; ad[5]=v1.y; ad[6]=v1.z; ad[7]=v1.w;
        v0 = *(const float4*)(att_edge + l * 8);
        v1 = *(const float4*)(att_edge + l * 8 + 4);
        ae[0]=v0.x; ae[1]=v0.y; ae[2]=v0.z; ae[3]=v0.w;
        ae[4]=v1.x; ae[5]=v1.y; ae[6]=v1.z; ae[7]=v1.w;
    }

    // score_src from own row
    float s_src;
    {
        uint4 u = *(const uint4*)(hA + (size_t)n * 512 + l * 8);
        float p = bf2f(u.x) * as[0] + bf2f(u.x >> 16) * as[1]
                + bf2f(u.y) * as[2] + bf2f(u.y >> 16) * as[3]
                + bf2f(u.z) * as[4] + bf2f(u.z >> 16) * as[5]
                + bf2f(u.w) * as[6] + bf2f(u.w >> 16) * as[7];
        p += __shfl_xor(p, 1);
        p += __shfl_xor(p, 2);
        p += __shfl_xor(p, 4);
        s_src = p;
    }

    float mrun = -1e30f, lsum = 0.f;
    float acc[8];
    #pragma unroll
    for (int j = 0; j < 8; ++j) acc[j] = 0.f;

    const int* pa = a2a + n * MAX_DEG;
    const int* pb = a2b + n * MAX_DEG;

    for (int d = 0; d < MAX_DEG; ++d) {
        int ia = pa[d];
        if (ia == 0) continue;             // wave-uniform; masked => weight 0 exactly
        int ib = pb[d];
        uint4 ua = *(const uint4*)(hA + (size_t)ia * 512 + l * 8);
        uint4 ub = *(const uint4*)(hB + (size_t)ib * 512 + l * 8);
        float fa[8], fb[8];
        fa[0]=bf2f(ua.x); fa[1]=bf2f(ua.x>>16); fa[2]=bf2f(ua.y); fa[3]=bf2f(ua.y>>16);
        fa[4]=bf2f(ua.z); fa[5]=bf2f(ua.z>>16); fa[6]=bf2f(ua.w); fa[7]=bf2f(ua.w>>16);
        fb[0]=bf2f(ub.x); fb[1]=bf2f(ub.x>>16); fb[2]=bf2f(ub.y); fb[3]=bf2f(ub.y>>16);
        fb[4]=bf2f(ub.z); fb[5]=bf2f(ub.z>>16); fb[6]=bf2f(ub.w); fb[7]=bf2f(ub.w>>16);

        float p = 0.f;
        #pragma unroll
        for (int j = 0; j < 8; ++j) p += fa[j] * ad[j] + fb[j] * ae[j];
        p += __shfl_xor(p, 1);
        p += __shfl_xor(p, 2);
        p += __shfl_xor(p, 4);

        float sc = s_src + p;
        sc = sc > 0.f ? sc : 0.2f * sc;    // leaky_relu(0.2)

        float mn = fmaxf(mrun, sc);
        float scale = __expf(mrun - mn);   // first iter: exp(-huge) = 0, acc/lsum are 0
        float pw = __expf(sc - mn);
        lsum = lsum * scale + pw;
        #pragma unroll
        for (int j = 0; j < 8; ++j)
            acc[j] = acc[j] * scale + pw * (fa[j] + fb[j]);
        mrun = mn;
    }

    float inv = lsum > 0.f ? 1.f / lsum : 0.f;
    float4 o0, o1;
    o0.x = acc[0]*inv; o0.y = acc[1]*inv; o0.z = acc[2]*inv; o0.w = acc[3]*inv;
    o1.x = acc[4]*inv; o1.y = acc[5]*inv; o1.z = acc[6]*inv; o1.w = acc[7]*inv;
    float* dst = out + (size_t)n * 512 + l * 8;
    *(float4*)dst = o0;
    *(float4*)(dst + 4) = o1;
}

// ---------------------------------------------------------------------------
extern "C" void kernel_launch(void* const* d_in, const int* in_sizes, int n_in,
                              void* d_out, int out_size, void* d_ws, size_t ws_size,
                              hipStream_t stream) {
    const float* x        = (const float*)d_in[0];
    const float* edge     = (const float*)d_in[1];
    const float* W_atom   = (const float*)d_in[2];
    const float* b_atom   = (const float*)d_in[3];
    const float* W_bond   = (const float*)d_in[4];
    const float* b_bond   = (const float*)d_in[5];
    const float* att_src  = (const float*)d_in[6];
    const float* att_dst  = (const float*)d_in[7];
    const float* att_edge = (const float*)d_in[8];
    const int*   a2a      = (const int*)d_in[9];
    const int*   a2b      = (const int*)d_in[10];
    float* out = (float*)d_out;

    char* ws = (char*)d_ws;
    unsigned short* hA  = (unsigned short*)ws;                               // 20,480,000 B
    unsigned short* hB  = (unsigned short*)(ws + 20480000);                  // 204,800,000 B
    unsigned short* WtA = (unsigned short*)(ws + 20480000 + 204800000);      // 262,144 B
    unsigned short* WtB = WtA + 512 * 256;                                   // 131,072 B

    wt_kernel<<<(512 * 256 + 255) / 256, 256, 0, stream>>>(W_atom, WtA, 256);
    wt_kernel<<<(512 * 128 + 255) / 256, 256, 0, stream>>>(W_bond, WtB, 128);

    gemm_kernel<<<313 * 8, 256, 0, stream>>>(x, WtA, b_atom, hA, N_ATOMS, 256);
    gemm_kernel<<<3125 * 8, 256, 0, stream>>>(edge, WtB, b_bond, hB, N_BONDS, 128);

    attn_kernel<<<(N_ATOMS + 3) / 4, 256, 0, stream>>>(
        hA, hB, att_src, att_dst, att_edge, a2a, a2b, out);
}